// Round 15
// baseline (194.815 us; speedup 1.0000x reference)
//
#include <hip/hip_runtime.h>
#include <hip/hip_bf16.h>

// CausalSelfAttention: B=4, T=2048, C=1024, H=16, HD=64
// Pipeline: x->bf16 | W->bf16^T | QKV GEMM (256^2, BK=32, ring-3 phase-structured
//           counted-vmcnt pipeline: 2 phases/K-tile, 16 MFMA/phase) |
//           flash attn (r14: 1024-block longest-first) | proj GEMM

typedef __attribute__((ext_vector_type(8))) short bf16x8;
typedef __attribute__((ext_vector_type(4))) float f32x4;
typedef __attribute__((ext_vector_type(4))) int int4v;

#define B_ 4
#define T_ 2048
#define C_ 1024
#define H_ 16
#define HD_ 64
#define SCALE_LOG2E 0.18033688011112042f   // (1/8) * log2(e), folded into Q at GEMM epilogue

__device__ __forceinline__ unsigned short f2bf(float f) {
    union { __hip_bfloat16 b; unsigned short u; } c;
    c.b = __float2bfloat16(f);
    return c.u;
}

// ---------------- x f32 -> bf16 ----------------
__global__ __launch_bounds__(256) void k_conv(const float* __restrict__ in,
                                              unsigned short* __restrict__ out, int n) {
    int i = (blockIdx.x * 256 + threadIdx.x) * 4;
    if (i >= n) return;
    float4 v = *(const float4*)(in + i);
    unsigned short r[4] = { f2bf(v.x), f2bf(v.y), f2bf(v.z), f2bf(v.w) };
    *(unsigned long long*)(out + i) = *(const unsigned long long*)r;
}

// ---------------- W [R][Cin] f32 -> out [Cin][R] bf16 (transpose+convert) ----------------
__global__ __launch_bounds__(256) void k_transp(const float* __restrict__ in,
                                                unsigned short* __restrict__ out,
                                                int R, int Cin) {
    __shared__ float t[32][33];
    int bx = blockIdx.x, by = blockIdx.y;
    int j = threadIdx.x & 31, i0 = threadIdx.x >> 5;
#pragma unroll
    for (int k = 0; k < 4; k++) {
        int i = i0 + k * 8;
        t[i][j] = in[(size_t)(by * 32 + i) * Cin + bx * 32 + j];
    }
    __syncthreads();
#pragma unroll
    for (int k = 0; k < 4; k++) {
        int c = i0 + k * 8;
        out[(size_t)(bx * 32 + c) * R + by * 32 + j] = f2bf(t[j][c]);
    }
}

// ---------------- QKV GEMM: 256x256 tile, BK=32, ring-3 phase pipeline ----------------
// A = xbf [8192][1024], BT = wqkvT [3072][1024]. 512 threads = 8 waves (2M x 4N),
// per-wave 128x64 output (8x4 frags). Per K-tile: 2 phases (quadrant mh=0/1), each
// {8 ds_read_b128, 2 global_load_lds (stage tile t+2 -> buf (t+2)%3, provably idle),
//  [vmcnt once/tile], s_barrier, setprio(1), 16 MFMA, setprio(0), s_barrier}.
// Counted vmcnt(4): at tile t outstanding = t+1(4 loads) + t+2(4) -> confirms t+1.
// BK=32 (64B rows): read pattern is bank-uniform (8 lanes/bank-quad) -> no swizzle,
// staging stays linear for global_load_lds.
#define QK_K 1024
#define QK_NT 32          // K tiles of 32
__global__ __launch_bounds__(512, 2) void k_qkv(
    const unsigned short* __restrict__ A, const unsigned short* __restrict__ BT,
    const float* __restrict__ bias,
    unsigned short* __restrict__ Qb, unsigned short* __restrict__ Kb,
    unsigned short* __restrict__ Vt)
{
    __shared__ unsigned short lds[3][16384];   // ring: [A 256x32 | B 256x32] = 32KB each

    const int tid = threadIdx.x;
    const int lane = tid & 63;
    const int w = tid >> 6;              // 0..7
    const int wm2 = w >> 2, wn4 = w & 3;
    const int l15 = lane & 15, lg = lane >> 4;

    // XCD-aware bijective swizzle: 384 blocks = 8 * 48
    const int orig = blockIdx.x;
    const int wg = (orig & 7) * 48 + (orig >> 3);
    const int bm = (wg / 12) * 256, bn = (wg % 12) * 256;

    const int srow4 = tid >> 2;          // 0..127 (row within a 128-row half)
    const int scol4 = (tid & 3) << 3;    // k-offset in shorts

    f32x4 acc[8][4];
#pragma unroll
    for (int mf = 0; mf < 8; mf++)
#pragma unroll
        for (int nf = 0; nf < 4; nf++) acc[mf][nf] = (f32x4){0.f, 0.f, 0.f, 0.f};

    // stage one 128-row half of tile t: mat 0=A, 1=B; h = which half (rows h*128..)
    auto stageHalf = [&](int t, int mat, int h) {
        const unsigned short* src = mat ? BT : A;
        const int rbase = (mat ? bn : bm) + h * 128 + srow4;
        __builtin_amdgcn_global_load_lds(
            (const __attribute__((address_space(1))) void*)
                (src + (size_t)rbase * QK_K + t * 32 + scol4),
            (__attribute__((address_space(3))) void*)
                (&lds[t % 3][mat * 8192 + h * 4096 + w * 512]),
            16, 0, 0);
    };

    // prologue: tiles 0 and 1 fully staged (4 loads each)
#pragma unroll
    for (int h = 0; h < 2; h++) { stageHalf(0, 0, h); stageHalf(0, 1, h); }
#pragma unroll
    for (int h = 0; h < 2; h++) { stageHalf(1, 0, h); stageHalf(1, 1, h); }
    asm volatile("s_waitcnt vmcnt(4)" ::: "memory");   // tile 0 confirmed
    __builtin_amdgcn_s_barrier();

#pragma unroll 1
    for (int t = 0; t < QK_NT; ++t) {
        const unsigned short* Bu = &lds[t % 3][0];
        const int u = t + 2;
#pragma unroll
        for (int mh = 0; mh < 2; ++mh) {
            // phase mh: register subtile for quadrant (4 m-frags x 4 n-frags)
            bf16x8 af[4], bfr[4];
#pragma unroll
            for (int q = 0; q < 4; ++q)
                af[q] = *(const bf16x8*)(Bu + (wm2 * 128 + mh * 64 + q * 16 + l15) * 32 + lg * 8);
#pragma unroll
            for (int nf = 0; nf < 4; ++nf)
                bfr[nf] = *(const bf16x8*)(Bu + 8192 + (wn4 * 64 + nf * 16 + l15) * 32 + lg * 8);

            // stage 2 halves of tile t+2 into the idle ring buffer
            if (u < QK_NT) { stageHalf(u, mh, 0); stageHalf(u, mh, 1); }

            if (mh == 1) {                     // once per tile: confirm tile t+1
                if (u < QK_NT) { asm volatile("s_waitcnt vmcnt(4)" ::: "memory"); }
                else           { asm volatile("s_waitcnt vmcnt(0)" ::: "memory"); }
            }
            __builtin_amdgcn_s_barrier();

            __builtin_amdgcn_s_setprio(1);
#pragma unroll
            for (int q = 0; q < 4; ++q)
#pragma unroll
                for (int nf = 0; nf < 4; ++nf)
                    acc[mh * 4 + q][nf] =
                        __builtin_amdgcn_mfma_f32_16x16x32_bf16(af[q], bfr[nf], acc[mh * 4 + q][nf], 0, 0, 0);
            __builtin_amdgcn_s_setprio(0);
            __builtin_amdgcn_s_barrier();
        }
    }

    // epilogue: bias + scatter Q (pre-scaled) / K bf16 [B,H,T,64], V -> Vt [B,H,64,T]
#pragma unroll
    for (int mf = 0; mf < 8; ++mf) {
#pragma unroll
        for (int nf = 0; nf < 4; ++nf) {
            int col = bn + wn4 * 64 + nf * 16 + l15;
            float bval = bias[col];
            int row0 = bm + wm2 * 128 + mf * 16 + lg * 4;
            float vals[4];
#pragma unroll
            for (int r = 0; r < 4; r++) vals[r] = acc[mf][nf][r] + bval;
            int b = row0 >> 11, t0 = row0 & 2047;
            int which = col >> 10;
            int h = (col & 1023) >> 6, d = col & 63;
            if (which == 2) {
                unsigned short pk[4];
#pragma unroll
                for (int r = 0; r < 4; r++) pk[r] = f2bf(vals[r]);
                *(unsigned long long*)(&Vt[((size_t)(b * H_ + h) * HD_ + d) * T_ + t0]) =
                    *(const unsigned long long*)pk;
            } else {
                unsigned short* dst = which ? Kb : Qb;
                float sc_ = which ? 1.0f : SCALE_LOG2E;
#pragma unroll
                for (int r = 0; r < 4; r++)
                    dst[((size_t)(b * H_ + h) * T_ + t0 + r) * HD_ + d] = f2bf(vals[r] * sc_);
            }
        }
    }
}

// ---------------- proj GEMM: m97 structure, 128^2 tile ----------------
__global__ __launch_bounds__(256) void k_proj(
    const unsigned short* __restrict__ A, const unsigned short* __restrict__ BT,
    const float* __restrict__ bias, float* __restrict__ out, int M, int N, int K)
{
    __shared__ unsigned short As[128][32];
    __shared__ unsigned short Bs[128][32];
    const int tid = threadIdx.x;
    const int lane = tid & 63;
    const int wv = tid >> 6;
    const int wm = wv >> 1, wn = wv & 1;
    const int l15 = lane & 15, lg = lane >> 4;

    const int nwg = gridDim.x * gridDim.y;
    const int orig = blockIdx.y * gridDim.x + blockIdx.x;
    const int wg = (orig & 7) * (nwg >> 3) + (orig >> 3);
    const int bm = (wg / gridDim.x) * 128, bn = (wg % gridDim.x) * 128;

    f32x4 acc[4][4];
#pragma unroll
    for (int m = 0; m < 4; m++)
#pragma unroll
        for (int n = 0; n < 4; n++) acc[m][n] = (f32x4){0.f, 0.f, 0.f, 0.f};

    const int rl = lane >> 2;
    const int cl = (lane & 3) * 8;

    for (int k0 = 0; k0 < K; k0 += 32) {
#pragma unroll
        for (int i = 0; i < 2; i++) {
            int c = wv + i * 4;
            __builtin_amdgcn_global_load_lds(
                (const __attribute__((address_space(1))) void*)
                    (&A[(size_t)(bm + c * 16 + rl) * K + k0 + cl]),
                (__attribute__((address_space(3))) void*)(&As[c * 16][0]), 16, 0, 0);
            __builtin_amdgcn_global_load_lds(
                (const __attribute__((address_space(1))) void*)
                    (&BT[(size_t)(bn + c * 16 + rl) * K + k0 + cl]),
                (__attribute__((address_space(3))) void*)(&Bs[c * 16][0]), 16, 0, 0);
        }
        __syncthreads();
        bf16x8 af[4], bfr[4];
#pragma unroll
        for (int m = 0; m < 4; m++) af[m]  = *(const bf16x8*)(&As[wm * 64 + m * 16 + l15][lg * 8]);
#pragma unroll
        for (int n = 0; n < 4; n++) bfr[n] = *(const bf16x8*)(&Bs[wn * 64 + n * 16 + l15][lg * 8]);
        __builtin_amdgcn_s_setprio(1);
#pragma unroll
        for (int m = 0; m < 4; m++)
#pragma unroll
            for (int n = 0; n < 4; n++)
                acc[m][n] = __builtin_amdgcn_mfma_f32_16x16x32_bf16(af[m], bfr[n], acc[m][n], 0, 0, 0);
        __builtin_amdgcn_s_setprio(0);
        __syncthreads();
    }

#pragma unroll
    for (int m = 0; m < 4; m++) {
#pragma unroll
        for (int n = 0; n < 4; n++) {
            int col = bn + wn * 64 + n * 16 + l15;
            float bval = bias[col];
            int row0 = bm + wm * 64 + m * 16 + lg * 4;
#pragma unroll
            for (int r = 0; r < 4; r++) out[(size_t)(row0 + r) * N + col] = acc[m][n][r] + bval;
        }
    }
}

// ---------------- Flash attention (causal): r14 (1024-block longest-first) ----------
__global__ __launch_bounds__(512, 4) void k_attn(
    const unsigned short* __restrict__ Qb, const unsigned short* __restrict__ Kb,
    const unsigned short* __restrict__ Vt, unsigned short* __restrict__ att)
{
    __shared__ unsigned short Ks[2][64][64];   // [buf][key][d], chunk16 ^= key&7
    __shared__ unsigned short Vs[2][64][64];   // [buf][d][newcol], chunk16 ^= d&7

    const int tid = threadIdx.x, lane = tid & 63, w = tid >> 6;   // w 0..7
    const int l15 = lane & 15, lg = lane >> 4;
    const int swq = l15 & 7;
    const int j = blockIdx.x;
    const int bh = j & 63;
    const int b = bh >> 4, h = bh & 15;
    const size_t kqbase = (size_t)bh * T_ * HD_;
    const size_t vtbase = (size_t)bh * HD_ * T_;

    const int r0 = tid >> 3;            // 0..63 staging row (one shot, 512 threads)
    const int mm = tid & 7;             // staging col chunk
    const int c8 = mm * 8;
    const int kch = mm;                               // K chunk (pre-swizzle)
    const int vch = 4 * (mm & 1) + (mm >> 2);         // V chunk half0 (pre-swizzle)
    const int voff = ((mm >> 1) & 1) * 4;             // shorts within chunk
    const int swr = r0 & 7;

    const int t = 15 - (j >> 6);            // longest-first 128-row q-tile
    const int qb = t * 128;
    const int qrow = qb + w * 16 + l15;     // this lane's q-row
    const int dtile = 2 * t + (w >> 2);     // wave-uniform diagonal tile
    const int ktlast = 2 * t + 1;           // block stages tiles 0..ktlast

    bf16x8 qf[2];
#pragma unroll
    for (int s = 0; s < 2; s++)
        qf[s] = *(const bf16x8*)(Qb + kqbase + (size_t)qrow * HD_ + s * 32 + lg * 8);

    f32x4 o[4];                   // o[cd][r] = O^T[d=cd*16+lg*4+r][q=l15]
    float m_run = -1e30f, l_run = 0.f;
#pragma unroll
    for (int c = 0; c < 4; c++) o[c] = (f32x4){0.f, 0.f, 0.f, 0.f};

    // prefetch tile 0
    int4v kreg, vreg;
    kreg = *(const int4v*)(Kb + kqbase + (size_t)r0 * HD_ + c8);
    vreg = *(const int4v*)(Vt + vtbase + (size_t)r0 * T_ + c8);

#pragma unroll 1
    for (int kt = 0; kt <= ktlast; ++kt) {
        const int bufi = kt & 1;
        *(int4v*)(&Ks[bufi][r0][(kch ^ swr) * 8]) = kreg;
        {
            unsigned long long vlo = ((const unsigned long long*)&vreg)[0];
            unsigned long long vhi = ((const unsigned long long*)&vreg)[1];
            *(unsigned long long*)(&Vs[bufi][r0][((vch       ^ swr) * 8) + voff]) = vlo;
            *(unsigned long long*)(&Vs[bufi][r0][(((vch + 2) ^ swr) * 8) + voff]) = vhi;
        }
        if (kt < ktlast) {                  // issue next tile's loads early (T14)
            int nk = (kt + 1) * 64;
            kreg = *(const int4v*)(Kb + kqbase + (size_t)(nk + r0) * HD_ + c8);
            vreg = *(const int4v*)(Vt + vtbase + (size_t)r0 * T_ + nk + c8);
        }
        __syncthreads();                    // single barrier per tile

        if (kt <= dtile) {
            // S^T = K Q^T : sv[c][r] = S[key=kt*64+c*16+lg*4+r][q=l15]
            float sv[4][4];
            const bool diag = (kt == dtile);
            __builtin_amdgcn_s_setprio(1);
#pragma unroll
            for (int c = 0; c < 4; c++) {
                bf16x8 kf0 = *(const bf16x8*)(&Ks[bufi][c * 16 + l15][(lg       ^ swq) * 8]);
                bf16x8 kf1 = *(const bf16x8*)(&Ks[bufi][c * 16 + l15][((4 + lg) ^ swq) * 8]);
                f32x4 s4 = (f32x4){0.f, 0.f, 0.f, 0.f};
                s4 = __builtin_amdgcn_mfma_f32_16x16x32_bf16(kf0, qf[0], s4, 0, 0, 0);
                s4 = __builtin_amdgcn_mfma_f32_16x16x32_bf16(kf1, qf[1], s4, 0, 0, 0);
                if (diag) {
                    int key0 = kt * 64 + c * 16 + lg * 4;
#pragma unroll
                    for (int r = 0; r < 4; r++)
                        sv[c][r] = (key0 + r > qrow) ? -1e30f : s4[r];
                } else {
#pragma unroll
                    for (int r = 0; r < 4; r++) sv[c][r] = s4[r];
                }
            }
            __builtin_amdgcn_s_setprio(0);

            // row max (whole q-row lane-local across 4 lane-group copies)
            float tm = fmaxf(fmaxf(fmaxf(sv[0][0], sv[0][1]), fmaxf(sv[0][2], sv[0][3])),
                             fmaxf(fmaxf(sv[1][0], sv[1][1]), fmaxf(sv[1][2], sv[1][3])));
            tm = fmaxf(tm, fmaxf(fmaxf(fmaxf(sv[2][0], sv[2][1]), fmaxf(sv[2][2], sv[2][3])),
                                 fmaxf(fmaxf(sv[3][0], sv[3][1]), fmaxf(sv[3][2], sv[3][3]))));
            tm = fmaxf(tm, __shfl_xor(tm, 16));
            tm = fmaxf(tm, __shfl_xor(tm, 32));

            // defer-max (T13): rescale only when a row's max grew past THR=8
            if (__any(tm - m_run > 8.f)) {
                float mn = fmaxf(m_run, tm);
                float alpha = exp2f(m_run - mn);
                m_run = mn;
                l_run *= alpha;
#pragma unroll
                for (int cd = 0; cd < 4; cd++)
#pragma unroll
                    for (int r = 0; r < 4; r++) o[cd][r] *= alpha;
            }

            // P in registers, packed per the kappa slot order (no LDS, no shuffles)
            float ps = 0.f;
            bf16x8 pf0, pf1;
#pragma unroll
            for (int c = 0; c < 2; c++)
#pragma unroll
                for (int r = 0; r < 4; r++) {
                    float pv0 = exp2f(sv[c][r] - m_run);
                    float pv1 = exp2f(sv[c + 2][r] - m_run);
                    ps += pv0 + pv1;
                    pf0[c * 4 + r] = (short)f2bf(pv0);
                    pf1[c * 4 + r] = (short)f2bf(pv1);
                }
            l_run += ps;

            // O^T += V~ P~ with matching slot->key map on both operands
            __builtin_amdgcn_s_setprio(1);
#pragma unroll
            for (int cd = 0; cd < 4; cd++) {
                bf16x8 vf0 = *(const bf16x8*)(&Vs[bufi][cd * 16 + l15][((2 * lg)     ^ swq) * 8]);
                bf16x8 vf1 = *(const bf16x8*)(&Vs[bufi][cd * 16 + l15][((2 * lg + 1) ^ swq) * 8]);
                o[cd] = __builtin_amdgcn_mfma_f32_16x16x32_bf16(vf0, pf0, o[cd], 0, 0, 0);
                o[cd] = __builtin_amdgcn_mfma_f32_16x16x32_bf16(vf1, pf1, o[cd], 0, 0, 0);
            }
            __builtin_amdgcn_s_setprio(0);
        }
    }

    // epilogue: cross-lane l reduce, normalize, store packed
    float ls = l_run;
    ls += __shfl_xor(ls, 16);
    ls += __shfl_xor(ls, 32);
    float inv = 1.0f / ls;
    const size_t rowbase = ((size_t)(b * T_ + qrow)) * C_ + h * 64;
#pragma unroll
    for (int cd = 0; cd < 4; cd++) {
        unsigned short ok[4];
#pragma unroll
        for (int r = 0; r < 4; r++) ok[r] = f2bf(o[cd][r] * inv);
        *(unsigned long long*)(&att[rowbase + cd * 16 + lg * 4]) =
            *(const unsigned long long*)ok;
    }
}

extern "C" void kernel_launch(void* const* d_in, const int* in_sizes, int n_in,
                              void* d_out, int out_size, void* d_ws, size_t ws_size,
                              hipStream_t stream)
{
    const float* x      = (const float*)d_in[0];
    const float* W_qkv  = (const float*)d_in[1];
    const float* b_qkv  = (const float*)d_in[2];
    const float* W_proj = (const float*)d_in[3];
    const float* b_proj = (const float*)d_in[4];
    float* out = (float*)d_out;

    char* p = (char*)d_ws;
    unsigned short* xbf    = (unsigned short*)p; p += (size_t)8192 * 1024 * 2;  // reused as att out
    unsigned short* wqkvT  = (unsigned short*)p; p += (size_t)3072 * 1024 * 2;
    unsigned short* wprojT = (unsigned short*)p; p += (size_t)1024 * 1024 * 2;
    unsigned short* Qb     = (unsigned short*)p; p += (size_t)8192 * 1024 * 2;
    unsigned short* Kb     = (unsigned short*)p; p += (size_t)8192 * 1024 * 2;
    unsigned short* Vt     = (unsigned short*)p; p += (size_t)8192 * 1024 * 2;  // [B*H, 64, T]

    k_conv<<<8192, 256, 0, stream>>>(x, xbf, 8192 * 1024);
    k_transp<<<dim3(96, 32), 256, 0, stream>>>(W_qkv, wqkvT, 1024, 3072);
    k_transp<<<dim3(32, 32), 256, 0, stream>>>(W_proj, wprojT, 1024, 1024);
    k_qkv<<<384, 512, 0, stream>>>(xbf, wqkvT, b_qkv, Qb, Kb, Vt);
    k_attn<<<1024, 512, 0, stream>>>(Qb, Kb, Vt, xbf);
    k_proj<<<dim3(8, 64), 256, 0, stream>>>(xbf, wprojT, b_proj, out, 8192, 1024, 1024);
}

// Round 16
// 190.013 us; speedup vs baseline: 1.0253x; 1.0253x over previous
//
#include <hip/hip_runtime.h>
#include <hip/hip_bf16.h>

// CausalSelfAttention: B=4, T=2048, C=1024, H=16, HD=64
// Pipeline: x->bf16 | W->bf16^T | QKV GEMM (256^2 ring-4 counted-vmcnt, r14 measured-best)
//           | flash attn (r14 grid + cvt_pk/max3 softmax diet) | proj GEMM

typedef __attribute__((ext_vector_type(8))) short bf16x8;
typedef __attribute__((ext_vector_type(4))) float f32x4;
typedef __attribute__((ext_vector_type(4))) int int4v;

#define B_ 4
#define T_ 2048
#define C_ 1024
#define H_ 16
#define HD_ 64
#define SCALE_LOG2E 0.18033688011112042f   // (1/8) * log2(e), folded into Q at GEMM epilogue

__device__ __forceinline__ unsigned short f2bf(float f) {
    union { __hip_bfloat16 b; unsigned short u; } c;
    c.b = __float2bfloat16(f);
    return c.u;
}

// hardware packed f32x2 -> bf16x2 (RNE), one VALU op
__device__ __forceinline__ unsigned cvtpk(float lo, float hi) {
    unsigned r;
    asm("v_cvt_pk_bf16_f32 %0, %1, %2" : "=v"(r) : "v"(lo), "v"(hi));
    return r;
}

// ---------------- x f32 -> bf16 ----------------
__global__ __launch_bounds__(256) void k_conv(const float* __restrict__ in,
                                              unsigned short* __restrict__ out, int n) {
    int i = (blockIdx.x * 256 + threadIdx.x) * 4;
    if (i >= n) return;
    float4 v = *(const float4*)(in + i);
    unsigned short r[4] = { f2bf(v.x), f2bf(v.y), f2bf(v.z), f2bf(v.w) };
    *(unsigned long long*)(out + i) = *(const unsigned long long*)r;
}

// ---------------- W [R][Cin] f32 -> out [Cin][R] bf16 (transpose+convert) ----------------
__global__ __launch_bounds__(256) void k_transp(const float* __restrict__ in,
                                                unsigned short* __restrict__ out,
                                                int R, int Cin) {
    __shared__ float t[32][33];
    int bx = blockIdx.x, by = blockIdx.y;
    int j = threadIdx.x & 31, i0 = threadIdx.x >> 5;
#pragma unroll
    for (int k = 0; k < 4; k++) {
        int i = i0 + k * 8;
        t[i][j] = in[(size_t)(by * 32 + i) * Cin + bx * 32 + j];
    }
    __syncthreads();
#pragma unroll
    for (int k = 0; k < 4; k++) {
        int c = i0 + k * 8;
        out[(size_t)(bx * 32 + c) * R + by * 32 + j] = f2bf(t[j][c]);
    }
}

// ---------------- QKV GEMM: 256x256 tile, BK=32, ring-4 counted-vmcnt (r14) ----------
#define QK_K 1024
#define QK_NT 32          // K tiles
__global__ __launch_bounds__(512, 2) void k_qkv(
    const unsigned short* __restrict__ A, const unsigned short* __restrict__ BT,
    const float* __restrict__ bias,
    unsigned short* __restrict__ Qb, unsigned short* __restrict__ Kb,
    unsigned short* __restrict__ Vt)
{
    __shared__ unsigned short lds[4][2][8192];   // [ring][A|B][256*32]

    const int tid = threadIdx.x;
    const int lane = tid & 63;
    const int w = tid >> 6;              // 0..7
    const int wm2 = w >> 2, wn4 = w & 3;
    const int l15 = lane & 15, lg = lane >> 4;

    // XCD-aware bijective swizzle: 384 blocks = 8 * 48
    const int orig = blockIdx.x;
    const int wg = (orig & 7) * 48 + (orig >> 3);
    const int bm = (wg / 12) * 256, bn = (wg % 12) * 256;

    const int srow = tid >> 2;           // + j*128
    const int scol = (tid & 3) << 3;     // k-offset in shorts

    f32x4 acc[8][4];
#pragma unroll
    for (int mf = 0; mf < 8; mf++)
#pragma unroll
        for (int nf = 0; nf < 4; nf++) acc[mf][nf] = (f32x4){0.f, 0.f, 0.f, 0.f};

    auto stage = [&](int Tt) {
        const int k0 = Tt << 5;
        const int rr = Tt & 3;
#pragma unroll
        for (int j = 0; j < 2; ++j) {
            __builtin_amdgcn_global_load_lds(
                (const __attribute__((address_space(1))) void*)
                    (A + (size_t)(bm + srow + j * 128) * QK_K + k0 + scol),
                (__attribute__((address_space(3))) void*)(&lds[rr][0][w * 512 + j * 4096]),
                16, 0, 0);
            __builtin_amdgcn_global_load_lds(
                (const __attribute__((address_space(1))) void*)
                    (BT + (size_t)(bn + srow + j * 128) * QK_K + k0 + scol),
                (__attribute__((address_space(3))) void*)(&lds[rr][1][w * 512 + j * 4096]),
                16, 0, 0);
        }
    };

    stage(0); stage(1); stage(2);        // 12 loads in flight

#pragma unroll 1
    for (int T = 0; T < QK_NT; ++T) {
        if (T <= QK_NT - 3)      { asm volatile("s_waitcnt vmcnt(8)" ::: "memory"); }
        else if (T == QK_NT - 2) { asm volatile("s_waitcnt vmcnt(4)" ::: "memory"); }
        else                     { asm volatile("s_waitcnt vmcnt(0)" ::: "memory"); }
        __builtin_amdgcn_s_barrier();    // publish tile T; reads of ring (T-1)&3 done
        if (T <= QK_NT - 4) stage(T + 3);

        const int rr = T & 3;
        const unsigned short* Ald = &lds[rr][0][0];
        const unsigned short* Bld = &lds[rr][1][0];
        bf16x8 af[8], bfr[4];
#pragma unroll
        for (int mf = 0; mf < 8; ++mf)
            af[mf] = *(const bf16x8*)(Ald + (wm2 * 128 + mf * 16 + l15) * 32 + lg * 8);
#pragma unroll
        for (int nf = 0; nf < 4; ++nf)
            bfr[nf] = *(const bf16x8*)(Bld + (wn4 * 64 + nf * 16 + l15) * 32 + lg * 8);

        __builtin_amdgcn_s_setprio(1);
#pragma unroll
        for (int mf = 0; mf < 8; ++mf)
#pragma unroll
            for (int nf = 0; nf < 4; ++nf)
                acc[mf][nf] = __builtin_amdgcn_mfma_f32_16x16x32_bf16(af[mf], bfr[nf], acc[mf][nf], 0, 0, 0);
        __builtin_amdgcn_s_setprio(0);
    }

    // epilogue: bias + scatter Q (pre-scaled) / K bf16 [B,H,T,64], V -> Vt [B,H,64,T]
#pragma unroll
    for (int mf = 0; mf < 8; ++mf) {
#pragma unroll
        for (int nf = 0; nf < 4; ++nf) {
            int col = bn + wn4 * 64 + nf * 16 + l15;
            float bval = bias[col];
            int row0 = bm + wm2 * 128 + mf * 16 + lg * 4;
            float vals[4];
#pragma unroll
            for (int r = 0; r < 4; r++) vals[r] = acc[mf][nf][r] + bval;
            int b = row0 >> 11, t0 = row0 & 2047;
            int which = col >> 10;
            int h = (col & 1023) >> 6, d = col & 63;
            if (which == 2) {
                unsigned short pk[4];
#pragma unroll
                for (int r = 0; r < 4; r++) pk[r] = f2bf(vals[r]);
                *(unsigned long long*)(&Vt[((size_t)(b * H_ + h) * HD_ + d) * T_ + t0]) =
                    *(const unsigned long long*)pk;
            } else {
                unsigned short* dst = which ? Kb : Qb;
                float sc_ = which ? 1.0f : SCALE_LOG2E;
#pragma unroll
                for (int r = 0; r < 4; r++)
                    dst[((size_t)(b * H_ + h) * T_ + t0 + r) * HD_ + d] = f2bf(vals[r] * sc_);
            }
        }
    }
}

// ---------------- proj GEMM: m97 structure, 128^2 tile ----------------
__global__ __launch_bounds__(256) void k_proj(
    const unsigned short* __restrict__ A, const unsigned short* __restrict__ BT,
    const float* __restrict__ bias, float* __restrict__ out, int M, int N, int K)
{
    __shared__ unsigned short As[128][32];
    __shared__ unsigned short Bs[128][32];
    const int tid = threadIdx.x;
    const int lane = tid & 63;
    const int wv = tid >> 6;
    const int wm = wv >> 1, wn = wv & 1;
    const int l15 = lane & 15, lg = lane >> 4;

    const int nwg = gridDim.x * gridDim.y;
    const int orig = blockIdx.y * gridDim.x + blockIdx.x;
    const int wg = (orig & 7) * (nwg >> 3) + (orig >> 3);
    const int bm = (wg / gridDim.x) * 128, bn = (wg % gridDim.x) * 128;

    f32x4 acc[4][4];
#pragma unroll
    for (int m = 0; m < 4; m++)
#pragma unroll
        for (int n = 0; n < 4; n++) acc[m][n] = (f32x4){0.f, 0.f, 0.f, 0.f};

    const int rl = lane >> 2;
    const int cl = (lane & 3) * 8;

    for (int k0 = 0; k0 < K; k0 += 32) {
#pragma unroll
        for (int i = 0; i < 2; i++) {
            int c = wv + i * 4;
            __builtin_amdgcn_global_load_lds(
                (const __attribute__((address_space(1))) void*)
                    (&A[(size_t)(bm + c * 16 + rl) * K + k0 + cl]),
                (__attribute__((address_space(3))) void*)(&As[c * 16][0]), 16, 0, 0);
            __builtin_amdgcn_global_load_lds(
                (const __attribute__((address_space(1))) void*)
                    (&BT[(size_t)(bn + c * 16 + rl) * K + k0 + cl]),
                (__attribute__((address_space(3))) void*)(&Bs[c * 16][0]), 16, 0, 0);
        }
        __syncthreads();
        bf16x8 af[4], bfr[4];
#pragma unroll
        for (int m = 0; m < 4; m++) af[m]  = *(const bf16x8*)(&As[wm * 64 + m * 16 + l15][lg * 8]);
#pragma unroll
        for (int n = 0; n < 4; n++) bfr[n] = *(const bf16x8*)(&Bs[wn * 64 + n * 16 + l15][lg * 8]);
        __builtin_amdgcn_s_setprio(1);
#pragma unroll
        for (int m = 0; m < 4; m++)
#pragma unroll
            for (int n = 0; n < 4; n++)
                acc[m][n] = __builtin_amdgcn_mfma_f32_16x16x32_bf16(af[m], bfr[n], acc[m][n], 0, 0, 0);
        __builtin_amdgcn_s_setprio(0);
        __syncthreads();
    }

#pragma unroll
    for (int m = 0; m < 4; m++) {
#pragma unroll
        for (int n = 0; n < 4; n++) {
            int col = bn + wn * 64 + n * 16 + l15;
            float bval = bias[col];
            int row0 = bm + wm * 64 + m * 16 + lg * 4;
#pragma unroll
            for (int r = 0; r < 4; r++) out[(size_t)(row0 + r) * N + col] = acc[m][n][r] + bval;
        }
    }
}

// ---------------- Flash attention (causal): r14 grid + softmax VALU diet ----------
// Q,K: [B*H, T, 64] (Q pre-scaled).  Vt: [B*H, 64, T].
// 1024 blocks (16 q-tiles x 64 heads), longest-first: t = 15-(j>>6), bh = j&63.
// 128 q-rows per block (16/wave x 8 waves). launch_bounds(512,4): VGPR ~48-64.
// Diet vs r14: (1) P-pack via v_cvt_pk_bf16_f32 (8 ops, was 16 software-RNE casts);
// (2) max-reduce as fmaxf triples -> clang fuses v_max3_f32.
__global__ __launch_bounds__(512, 4) void k_attn(
    const unsigned short* __restrict__ Qb, const unsigned short* __restrict__ Kb,
    const unsigned short* __restrict__ Vt, unsigned short* __restrict__ att)
{
    __shared__ unsigned short Ks[2][64][64];   // [buf][key][d], chunk16 ^= key&7
    __shared__ unsigned short Vs[2][64][64];   // [buf][d][newcol], chunk16 ^= d&7

    const int tid = threadIdx.x, lane = tid & 63, w = tid >> 6;   // w 0..7
    const int l15 = lane & 15, lg = lane >> 4;
    const int swq = l15 & 7;
    const int j = blockIdx.x;
    const int bh = j & 63;
    const int b = bh >> 4, h = bh & 15;
    const size_t kqbase = (size_t)bh * T_ * HD_;
    const size_t vtbase = (size_t)bh * HD_ * T_;

    const int r0 = tid >> 3;            // 0..63 staging row (one shot, 512 threads)
    const int mm = tid & 7;             // staging col chunk
    const int c8 = mm * 8;
    const int kch = mm;                               // K chunk (pre-swizzle)
    const int vch = 4 * (mm & 1) + (mm >> 2);         // V chunk half0 (pre-swizzle)
    const int voff = ((mm >> 1) & 1) * 4;             // shorts within chunk
    const int swr = r0 & 7;

    const int t = 15 - (j >> 6);            // longest-first 128-row q-tile
    const int qb = t * 128;
    const int qrow = qb + w * 16 + l15;     // this lane's q-row
    const int dtile = 2 * t + (w >> 2);     // wave-uniform diagonal tile
    const int ktlast = 2 * t + 1;           // block stages tiles 0..ktlast

    bf16x8 qf[2];
#pragma unroll
    for (int s = 0; s < 2; s++)
        qf[s] = *(const bf16x8*)(Qb + kqbase + (size_t)qrow * HD_ + s * 32 + lg * 8);

    f32x4 o[4];                   // o[cd][r] = O^T[d=cd*16+lg*4+r][q=l15]
    float m_run = -1e30f, l_run = 0.f;
#pragma unroll
    for (int c = 0; c < 4; c++) o[c] = (f32x4){0.f, 0.f, 0.f, 0.f};

    // prefetch tile 0
    int4v kreg, vreg;
    kreg = *(const int4v*)(Kb + kqbase + (size_t)r0 * HD_ + c8);
    vreg = *(const int4v*)(Vt + vtbase + (size_t)r0 * T_ + c8);

#pragma unroll 1
    for (int kt = 0; kt <= ktlast; ++kt) {
        const int bufi = kt & 1;
        *(int4v*)(&Ks[bufi][r0][(kch ^ swr) * 8]) = kreg;
        {
            unsigned long long vlo = ((const unsigned long long*)&vreg)[0];
            unsigned long long vhi = ((const unsigned long long*)&vreg)[1];
            *(unsigned long long*)(&Vs[bufi][r0][((vch       ^ swr) * 8) + voff]) = vlo;
            *(unsigned long long*)(&Vs[bufi][r0][(((vch + 2) ^ swr) * 8) + voff]) = vhi;
        }
        if (kt < ktlast) {                  // issue next tile's loads early (T14)
            int nk = (kt + 1) * 64;
            kreg = *(const int4v*)(Kb + kqbase + (size_t)(nk + r0) * HD_ + c8);
            vreg = *(const int4v*)(Vt + vtbase + (size_t)r0 * T_ + nk + c8);
        }
        __syncthreads();                    // single barrier per tile

        if (kt <= dtile) {
            // S^T = K Q^T : sv[c][r] = S[key=kt*64+c*16+lg*4+r][q=l15]
            float sv[4][4];
            const bool diag = (kt == dtile);
            __builtin_amdgcn_s_setprio(1);
#pragma unroll
            for (int c = 0; c < 4; c++) {
                bf16x8 kf0 = *(const bf16x8*)(&Ks[bufi][c * 16 + l15][(lg       ^ swq) * 8]);
                bf16x8 kf1 = *(const bf16x8*)(&Ks[bufi][c * 16 + l15][((4 + lg) ^ swq) * 8]);
                f32x4 s4 = (f32x4){0.f, 0.f, 0.f, 0.f};
                s4 = __builtin_amdgcn_mfma_f32_16x16x32_bf16(kf0, qf[0], s4, 0, 0, 0);
                s4 = __builtin_amdgcn_mfma_f32_16x16x32_bf16(kf1, qf[1], s4, 0, 0, 0);
                if (diag) {
                    int key0 = kt * 64 + c * 16 + lg * 4;
#pragma unroll
                    for (int r = 0; r < 4; r++)
                        sv[c][r] = (key0 + r > qrow) ? -1e30f : s4[r];
                } else {
#pragma unroll
                    for (int r = 0; r < 4; r++) sv[c][r] = s4[r];
                }
            }
            __builtin_amdgcn_s_setprio(0);

            // row max: fmaxf-triples so clang fuses v_max3_f32 (T17)
            float a0 = fmaxf(fmaxf(sv[0][0], sv[0][1]), sv[0][2]);
            float a1 = fmaxf(fmaxf(sv[0][3], sv[1][0]), sv[1][1]);
            float a2 = fmaxf(fmaxf(sv[1][2], sv[1][3]), sv[2][0]);
            float a3 = fmaxf(fmaxf(sv[2][1], sv[2][2]), sv[2][3]);
            float a4 = fmaxf(fmaxf(sv[3][0], sv[3][1]), sv[3][2]);
            float tm = fmaxf(fmaxf(fmaxf(a0, a1), a2), fmaxf(fmaxf(a3, a4), sv[3][3]));
            tm = fmaxf(tm, __shfl_xor(tm, 16));
            tm = fmaxf(tm, __shfl_xor(tm, 32));

            // defer-max (T13): rescale only when a row's max grew past THR=8
            if (__any(tm - m_run > 8.f)) {
                float mn = fmaxf(m_run, tm);
                float alpha = exp2f(m_run - mn);
                m_run = mn;
                l_run *= alpha;
#pragma unroll
                for (int cd = 0; cd < 4; cd++)
#pragma unroll
                    for (int r = 0; r < 4; r++) o[cd][r] *= alpha;
            }

            // P in registers (kappa slot order), packed by hardware cvt_pk (T12 recipe)
            float ps = 0.f;
            union { unsigned u[4]; bf16x8 v; } P0, P1;
#pragma unroll
            for (int c = 0; c < 2; c++)
#pragma unroll
                for (int rp = 0; rp < 2; rp++) {
                    float e0 = exp2f(sv[c][2 * rp]         - m_run);
                    float e1 = exp2f(sv[c][2 * rp + 1]     - m_run);
                    float e2 = exp2f(sv[c + 2][2 * rp]     - m_run);
                    float e3 = exp2f(sv[c + 2][2 * rp + 1] - m_run);
                    ps += (e0 + e1) + (e2 + e3);
                    P0.u[c * 2 + rp] = cvtpk(e0, e1);
                    P1.u[c * 2 + rp] = cvtpk(e2, e3);
                }
            l_run += ps;

            // O^T += V~ P~ with matching slot->key map on both operands
            __builtin_amdgcn_s_setprio(1);
#pragma unroll
            for (int cd = 0; cd < 4; cd++) {
                bf16x8 vf0 = *(const bf16x8*)(&Vs[bufi][cd * 16 + l15][((2 * lg)     ^ swq) * 8]);
                bf16x8 vf1 = *(const bf16x8*)(&Vs[bufi][cd * 16 + l15][((2 * lg + 1) ^ swq) * 8]);
                o[cd] = __builtin_amdgcn_mfma_f32_16x16x32_bf16(vf0, P0.v, o[cd], 0, 0, 0);
                o[cd] = __builtin_amdgcn_mfma_f32_16x16x32_bf16(vf1, P1.v, o[cd], 0, 0, 0);
            }
            __builtin_amdgcn_s_setprio(0);
        }
    }

    // epilogue: cross-lane l reduce, normalize, store packed
    float ls = l_run;
    ls += __shfl_xor(ls, 16);
    ls += __shfl_xor(ls, 32);
    float inv = 1.0f / ls;
    const size_t rowbase = ((size_t)(b * T_ + qrow)) * C_ + h * 64;
#pragma unroll
    for (int cd = 0; cd < 4; cd++) {
        unsigned ok2[2];
        ok2[0] = cvtpk(o[cd][0] * inv, o[cd][1] * inv);
        ok2[1] = cvtpk(o[cd][2] * inv, o[cd][3] * inv);
        *(unsigned long long*)(&att[rowbase + cd * 16 + lg * 4]) =
            *(const unsigned long long*)ok2;
    }
}

extern "C" void kernel_launch(void* const* d_in, const int* in_sizes, int n_in,
                              void* d_out, int out_size, void* d_ws, size_t ws_size,
                              hipStream_t stream)
{
    const float* x      = (const float*)d_in[0];
    const float* W_qkv  = (const float*)d_in[1];
    const float* b_qkv  = (const float*)d_in[2];
    const float* W_proj = (const float*)d_in[3];
    const float* b_proj = (const float*)d_in[4];
    float* out = (float*)d_out;

    char* p = (char*)d_ws;
    unsigned short* xbf    = (unsigned short*)p; p += (size_t)8192 * 1024 * 2;  // reused as att out
    unsigned short* wqkvT  = (unsigned short*)p; p += (size_t)3072 * 1024 * 2;
    unsigned short* wprojT = (unsigned short*)p; p += (size_t)1024 * 1024 * 2;
    unsigned short* Qb     = (unsigned short*)p; p += (size_t)8192 * 1024 * 2;
    unsigned short* Kb     = (unsigned short*)p; p += (size_t)8192 * 1024 * 2;
    unsigned short* Vt     = (unsigned short*)p; p += (size_t)8192 * 1024 * 2;  // [B*H, 64, T]

    k_conv<<<8192, 256, 0, stream>>>(x, xbf, 8192 * 1024);
    k_transp<<<dim3(96, 32), 256, 0, stream>>>(W_qkv, wqkvT, 1024, 3072);
    k_transp<<<dim3(32, 32), 256, 0, stream>>>(W_proj, wprojT, 1024, 1024);
    k_qkv<<<384, 512, 0, stream>>>(xbf, wqkvT, b_qkv, Qb, Kb, Vt);
    k_attn<<<1024, 512, 0, stream>>>(Qb, Kb, Vt, xbf);
    k_proj<<<dim3(8, 64), 256, 0, stream>>>(xbf, wprojT, b_proj, out, 8192, 1024, 1024);
}

// Round 17
// 186.481 us; speedup vs baseline: 1.0447x; 1.0189x over previous
//
#include <hip/hip_runtime.h>
#include <hip/hip_bf16.h>

// CausalSelfAttention: B=4, T=2048, C=1024, H=16, HD=64
// Pipeline: x->bf16 | W->bf16^T | QKV GEMM (256x192 tile, ring-4 counted-vmcnt,
//           512 blocks = 2.0 exact CU rounds) | flash attn (r16) | proj GEMM

typedef __attribute__((ext_vector_type(8))) short bf16x8;
typedef __attribute__((ext_vector_type(4))) float f32x4;
typedef __attribute__((ext_vector_type(4))) int int4v;

#define B_ 4
#define T_ 2048
#define C_ 1024
#define H_ 16
#define HD_ 64
#define SCALE_LOG2E 0.18033688011112042f   // (1/8) * log2(e), folded into Q at GEMM epilogue

__device__ __forceinline__ unsigned short f2bf(float f) {
    union { __hip_bfloat16 b; unsigned short u; } c;
    c.b = __float2bfloat16(f);
    return c.u;
}

// hardware packed f32x2 -> bf16x2 (RNE), one VALU op
__device__ __forceinline__ unsigned cvtpk(float lo, float hi) {
    unsigned r;
    asm("v_cvt_pk_bf16_f32 %0, %1, %2" : "=v"(r) : "v"(lo), "v"(hi));
    return r;
}

// ---------------- x f32 -> bf16 ----------------
__global__ __launch_bounds__(256) void k_conv(const float* __restrict__ in,
                                              unsigned short* __restrict__ out, int n) {
    int i = (blockIdx.x * 256 + threadIdx.x) * 4;
    if (i >= n) return;
    float4 v = *(const float4*)(in + i);
    unsigned short r[4] = { f2bf(v.x), f2bf(v.y), f2bf(v.z), f2bf(v.w) };
    *(unsigned long long*)(out + i) = *(const unsigned long long*)r;
}

// ---------------- W [R][Cin] f32 -> out [Cin][R] bf16 (transpose+convert) ----------------
__global__ __launch_bounds__(256) void k_transp(const float* __restrict__ in,
                                                unsigned short* __restrict__ out,
                                                int R, int Cin) {
    __shared__ float t[32][33];
    int bx = blockIdx.x, by = blockIdx.y;
    int j = threadIdx.x & 31, i0 = threadIdx.x >> 5;
#pragma unroll
    for (int k = 0; k < 4; k++) {
        int i = i0 + k * 8;
        t[i][j] = in[(size_t)(by * 32 + i) * Cin + bx * 32 + j];
    }
    __syncthreads();
#pragma unroll
    for (int k = 0; k < 4; k++) {
        int c = i0 + k * 8;
        out[(size_t)(bx * 32 + c) * R + by * 32 + j] = f2bf(t[j][c]);
    }
}

// ---------------- QKV GEMM: 256x192 tile, BK=32, ring-4 counted-vmcnt ----------------
// A = xbf [8192][1024], BT = wqkvT [3072][1024]. 512 threads = 8 waves (2M x 4N),
// per-wave 128x48 output (8x3 frags), 24 MFMA + 11 ds_read_b128 per K-tile.
// Grid 512 = 32 Mtiles x 16 Ntiles = 2.0 EXACT rounds at 1 block/CU (fixes the
// 384-block 1.5-round quantization tax measured in r10-r16).
// Staging per thread per tile: A 2x16B (all), B: waves 0-3 2x16B, waves 4-7 1x16B
// (192 rows = 768 chunk-loads over 512 threads). Wave-uniform load count L = 4 / 3
// -> counted vmcnt is wave-dependent: steady 2L (8/6), drain L (4/3), then 0.
// Ring-4 hazard: stage(T+3) targets buf (T-1)&3, whose reads completed before the
// iter-T barrier (consumed by MFMAs) -- same schedule validated in r14.
#define QK_K 1024
#define QK_NT 32          // K tiles
__global__ __launch_bounds__(512, 2) void k_qkv(
    const unsigned short* __restrict__ A, const unsigned short* __restrict__ BT,
    const float* __restrict__ bias,
    unsigned short* __restrict__ Qb, unsigned short* __restrict__ Kb,
    unsigned short* __restrict__ Vt)
{
    __shared__ unsigned short lds[4][14336];   // ring: A 256x32 (8192) | B 192x32 (6144)

    const int tid = threadIdx.x;
    const int lane = tid & 63;
    const int w = tid >> 6;              // 0..7
    const int wm2 = w >> 2, wn4 = w & 3;
    const int l15 = lane & 15, lg = lane >> 4;

    // XCD-aware bijective swizzle: 512 blocks = 8 * 64
    const int orig = blockIdx.x;
    const int wg = (orig & 7) * 64 + (orig >> 3);
    const int bm = (wg >> 4) * 256, bn = (wg & 15) * 192;

    const int srow = tid >> 2;           // 0..127
    const int scol = (tid & 3) << 3;     // k-offset in shorts

    f32x4 acc[8][3];
#pragma unroll
    for (int mf = 0; mf < 8; mf++)
#pragma unroll
        for (int nf = 0; nf < 3; nf++) acc[mf][nf] = (f32x4){0.f, 0.f, 0.f, 0.f};

    auto stage = [&](int Tt) {
        const int k0 = Tt << 5;
        const int rr = Tt & 3;
        // A: 256 rows, 2 loads/thread
#pragma unroll
        for (int j = 0; j < 2; ++j)
            __builtin_amdgcn_global_load_lds(
                (const __attribute__((address_space(1))) void*)
                    (A + (size_t)(bm + srow + j * 128) * QK_K + k0 + scol),
                (__attribute__((address_space(3))) void*)(&lds[rr][w * 512 + j * 4096]),
                16, 0, 0);
        // B rows 0..127: 1 load/thread (all waves)
        __builtin_amdgcn_global_load_lds(
            (const __attribute__((address_space(1))) void*)
                (BT + (size_t)(bn + srow) * QK_K + k0 + scol),
            (__attribute__((address_space(3))) void*)(&lds[rr][8192 + w * 512]),
            16, 0, 0);
        // B rows 128..191: 1 load/thread, waves 0-3 only (wave-uniform branch)
        if (w < 4)
            __builtin_amdgcn_global_load_lds(
                (const __attribute__((address_space(1))) void*)
                    (BT + (size_t)(bn + 128 + srow) * QK_K + k0 + scol),
                (__attribute__((address_space(3))) void*)(&lds[rr][8192 + 4096 + w * 512]),
                16, 0, 0);
    };

    stage(0); stage(1); stage(2);        // 3 tiles in flight (L loads each)

#pragma unroll 1
    for (int T = 0; T < QK_NT; ++T) {
        // confirm tile T: outstanding = stages T..T+2 (3L); skip newer 2L
        if (T <= QK_NT - 3) {
            if (w < 4) { asm volatile("s_waitcnt vmcnt(8)" ::: "memory"); }
            else       { asm volatile("s_waitcnt vmcnt(6)" ::: "memory"); }
        } else if (T == QK_NT - 2) {
            if (w < 4) { asm volatile("s_waitcnt vmcnt(4)" ::: "memory"); }
            else       { asm volatile("s_waitcnt vmcnt(3)" ::: "memory"); }
        } else {
            asm volatile("s_waitcnt vmcnt(0)" ::: "memory");
        }
        __builtin_amdgcn_s_barrier();    // publish tile T
        if (T <= QK_NT - 4) stage(T + 3);

        const int rr = T & 3;
        const unsigned short* Ald = &lds[rr][0];
        const unsigned short* Bld = &lds[rr][8192];
        bf16x8 af[8], bfr[3];
#pragma unroll
        for (int mf = 0; mf < 8; ++mf)
            af[mf] = *(const bf16x8*)(Ald + (wm2 * 128 + mf * 16 + l15) * 32 + lg * 8);
#pragma unroll
        for (int nf = 0; nf < 3; ++nf)
            bfr[nf] = *(const bf16x8*)(Bld + (wn4 * 48 + nf * 16 + l15) * 32 + lg * 8);

        __builtin_amdgcn_s_setprio(1);
#pragma unroll
        for (int mf = 0; mf < 8; ++mf)
#pragma unroll
            for (int nf = 0; nf < 3; ++nf)
                acc[mf][nf] = __builtin_amdgcn_mfma_f32_16x16x32_bf16(af[mf], bfr[nf], acc[mf][nf], 0, 0, 0);
        __builtin_amdgcn_s_setprio(0);
    }

    // epilogue: bias + scatter Q (pre-scaled) / K bf16 [B,H,T,64], V -> Vt [B,H,64,T]
#pragma unroll
    for (int mf = 0; mf < 8; ++mf) {
#pragma unroll
        for (int nf = 0; nf < 3; ++nf) {
            int col = bn + wn4 * 48 + nf * 16 + l15;
            float bval = bias[col];
            int row0 = bm + wm2 * 128 + mf * 16 + lg * 4;
            float vals[4];
#pragma unroll
            for (int r = 0; r < 4; r++) vals[r] = acc[mf][nf][r] + bval;
            int b = row0 >> 11, t0 = row0 & 2047;
            int which = col >> 10;
            int h = (col & 1023) >> 6, d = col & 63;
            if (which == 2) {
                unsigned short pk[4];
#pragma unroll
                for (int r = 0; r < 4; r++) pk[r] = f2bf(vals[r]);
                *(unsigned long long*)(&Vt[((size_t)(b * H_ + h) * HD_ + d) * T_ + t0]) =
                    *(const unsigned long long*)pk;
            } else {
                unsigned short* dst = which ? Kb : Qb;
                float sc_ = which ? 1.0f : SCALE_LOG2E;
#pragma unroll
                for (int r = 0; r < 4; r++)
                    dst[((size_t)(b * H_ + h) * T_ + t0 + r) * HD_ + d] = f2bf(vals[r] * sc_);
            }
        }
    }
}

// ---------------- proj GEMM: m97 structure, 128^2 tile ----------------
__global__ __launch_bounds__(256) void k_proj(
    const unsigned short* __restrict__ A, const unsigned short* __restrict__ BT,
    const float* __restrict__ bias, float* __restrict__ out, int M, int N, int K)
{
    __shared__ unsigned short As[128][32];
    __shared__ unsigned short Bs[128][32];
    const int tid = threadIdx.x;
    const int lane = tid & 63;
    const int wv = tid >> 6;
    const int wm = wv >> 1, wn = wv & 1;
    const int l15 = lane & 15, lg = lane >> 4;

    const int nwg = gridDim.x * gridDim.y;
    const int orig = blockIdx.y * gridDim.x + blockIdx.x;
    const int wg = (orig & 7) * (nwg >> 3) + (orig >> 3);
    const int bm = (wg / gridDim.x) * 128, bn = (wg % gridDim.x) * 128;

    f32x4 acc[4][4];
#pragma unroll
    for (int m = 0; m < 4; m++)
#pragma unroll
        for (int n = 0; n < 4; n++) acc[m][n] = (f32x4){0.f, 0.f, 0.f, 0.f};

    const int rl = lane >> 2;
    const int cl = (lane & 3) * 8;

    for (int k0 = 0; k0 < K; k0 += 32) {
#pragma unroll
        for (int i = 0; i < 2; i++) {
            int c = wv + i * 4;
            __builtin_amdgcn_global_load_lds(
                (const __attribute__((address_space(1))) void*)
                    (&A[(size_t)(bm + c * 16 + rl) * K + k0 + cl]),
                (__attribute__((address_space(3))) void*)(&As[c * 16][0]), 16, 0, 0);
            __builtin_amdgcn_global_load_lds(
                (const __attribute__((address_space(1))) void*)
                    (&BT[(size_t)(bn + c * 16 + rl) * K + k0 + cl]),
                (__attribute__((address_space(3))) void*)(&Bs[c * 16][0]), 16, 0, 0);
        }
        __syncthreads();
        bf16x8 af[4], bfr[4];
#pragma unroll
        for (int m = 0; m < 4; m++) af[m]  = *(const bf16x8*)(&As[wm * 64 + m * 16 + l15][lg * 8]);
#pragma unroll
        for (int n = 0; n < 4; n++) bfr[n] = *(const bf16x8*)(&Bs[wn * 64 + n * 16 + l15][lg * 8]);
        __builtin_amdgcn_s_setprio(1);
#pragma unroll
        for (int m = 0; m < 4; m++)
#pragma unroll
            for (int n = 0; n < 4; n++)
                acc[m][n] = __builtin_amdgcn_mfma_f32_16x16x32_bf16(af[m], bfr[n], acc[m][n], 0, 0, 0);
        __builtin_amdgcn_s_setprio(0);
        __syncthreads();
    }

#pragma unroll
    for (int m = 0; m < 4; m++) {
#pragma unroll
        for (int n = 0; n < 4; n++) {
            int col = bn + wn * 64 + n * 16 + l15;
            float bval = bias[col];
            int row0 = bm + wm * 64 + m * 16 + lg * 4;
#pragma unroll
            for (int r = 0; r < 4; r++) out[(size_t)(row0 + r) * N + col] = acc[m][n][r] + bval;
        }
    }
}

// ---------------- Flash attention (causal): r16 (r14 grid + softmax diet) ----------
__global__ __launch_bounds__(512, 4) void k_attn(
    const unsigned short* __restrict__ Qb, const unsigned short* __restrict__ Kb,
    const unsigned short* __restrict__ Vt, unsigned short* __restrict__ att)
{
    __shared__ unsigned short Ks[2][64][64];   // [buf][key][d], chunk16 ^= key&7
    __shared__ unsigned short Vs[2][64][64];   // [buf][d][newcol], chunk16 ^= d&7

    const int tid = threadIdx.x, lane = tid & 63, w = tid >> 6;   // w 0..7
    const int l15 = lane & 15, lg = lane >> 4;
    const int swq = l15 & 7;
    const int j = blockIdx.x;
    const int bh = j & 63;
    const int b = bh >> 4, h = bh & 15;
    const size_t kqbase = (size_t)bh * T_ * HD_;
    const size_t vtbase = (size_t)bh * HD_ * T_;

    const int r0 = tid >> 3;            // 0..63 staging row (one shot, 512 threads)
    const int mm = tid & 7;             // staging col chunk
    const int c8 = mm * 8;
    const int kch = mm;                               // K chunk (pre-swizzle)
    const int vch = 4 * (mm & 1) + (mm >> 2);         // V chunk half0 (pre-swizzle)
    const int voff = ((mm >> 1) & 1) * 4;             // shorts within chunk
    const int swr = r0 & 7;

    const int t = 15 - (j >> 6);            // longest-first 128-row q-tile
    const int qb = t * 128;
    const int qrow = qb + w * 16 + l15;     // this lane's q-row
    const int dtile = 2 * t + (w >> 2);     // wave-uniform diagonal tile
    const int ktlast = 2 * t + 1;           // block stages tiles 0..ktlast

    bf16x8 qf[2];
#pragma unroll
    for (int s = 0; s < 2; s++)
        qf[s] = *(const bf16x8*)(Qb + kqbase + (size_t)qrow * HD_ + s * 32 + lg * 8);

    f32x4 o[4];                   // o[cd][r] = O^T[d=cd*16+lg*4+r][q=l15]
    float m_run = -1e30f, l_run = 0.f;
#pragma unroll
    for (int c = 0; c < 4; c++) o[c] = (f32x4){0.f, 0.f, 0.f, 0.f};

    // prefetch tile 0
    int4v kreg, vreg;
    kreg = *(const int4v*)(Kb + kqbase + (size_t)r0 * HD_ + c8);
    vreg = *(const int4v*)(Vt + vtbase + (size_t)r0 * T_ + c8);

#pragma unroll 1
    for (int kt = 0; kt <= ktlast; ++kt) {
        const int bufi = kt & 1;
        *(int4v*)(&Ks[bufi][r0][(kch ^ swr) * 8]) = kreg;
        {
            unsigned long long vlo = ((const unsigned long long*)&vreg)[0];
            unsigned long long vhi = ((const unsigned long long*)&vreg)[1];
            *(unsigned long long*)(&Vs[bufi][r0][((vch       ^ swr) * 8) + voff]) = vlo;
            *(unsigned long long*)(&Vs[bufi][r0][(((vch + 2) ^ swr) * 8) + voff]) = vhi;
        }
        if (kt < ktlast) {                  // issue next tile's loads early (T14)
            int nk = (kt + 1) * 64;
            kreg = *(const int4v*)(Kb + kqbase + (size_t)(nk + r0) * HD_ + c8);
            vreg = *(const int4v*)(Vt + vtbase + (size_t)r0 * T_ + nk + c8);
        }
        __syncthreads();                    // single barrier per tile

        if (kt <= dtile) {
            // S^T = K Q^T : sv[c][r] = S[key=kt*64+c*16+lg*4+r][q=l15]
            float sv[4][4];
            const bool diag = (kt == dtile);
            __builtin_amdgcn_s_setprio(1);
#pragma unroll
            for (int c = 0; c < 4; c++) {
                bf16x8 kf0 = *(const bf16x8*)(&Ks[bufi][c * 16 + l15][(lg       ^ swq) * 8]);
                bf16x8 kf1 = *(const bf16x8*)(&Ks[bufi][c * 16 + l15][((4 + lg) ^ swq) * 8]);
                f32x4 s4 = (f32x4){0.f, 0.f, 0.f, 0.f};
                s4 = __builtin_amdgcn_mfma_f32_16x16x32_bf16(kf0, qf[0], s4, 0, 0, 0);
                s4 = __builtin_amdgcn_mfma_f32_16x16x32_bf16(kf1, qf[1], s4, 0, 0, 0);
                if (diag) {
                    int key0 = kt * 64 + c * 16 + lg * 4;
#pragma unroll
                    for (int r = 0; r < 4; r++)
                        sv[c][r] = (key0 + r > qrow) ? -1e30f : s4[r];
                } else {
#pragma unroll
                    for (int r = 0; r < 4; r++) sv[c][r] = s4[r];
                }
            }
            __builtin_amdgcn_s_setprio(0);

            // row max: fmaxf-triples so clang fuses v_max3_f32 (T17)
            float a0 = fmaxf(fmaxf(sv[0][0], sv[0][1]), sv[0][2]);
            float a1 = fmaxf(fmaxf(sv[0][3], sv[1][0]), sv[1][1]);
            float a2 = fmaxf(fmaxf(sv[1][2], sv[1][3]), sv[2][0]);
            float a3 = fmaxf(fmaxf(sv[2][1], sv[2][2]), sv[2][3]);
            float a4 = fmaxf(fmaxf(sv[3][0], sv[3][1]), sv[3][2]);
            float tm = fmaxf(fmaxf(fmaxf(a0, a1), a2), fmaxf(fmaxf(a3, a4), sv[3][3]));
            tm = fmaxf(tm, __shfl_xor(tm, 16));
            tm = fmaxf(tm, __shfl_xor(tm, 32));

            // defer-max (T13): rescale only when a row's max grew past THR=8
            if (__any(tm - m_run > 8.f)) {
                float mn = fmaxf(m_run, tm);
                float alpha = exp2f(m_run - mn);
                m_run = mn;
                l_run *= alpha;
#pragma unroll
                for (int cd = 0; cd < 4; cd++)
#pragma unroll
                    for (int r = 0; r < 4; r++) o[cd][r] *= alpha;
            }

            // P in registers (kappa slot order), packed by hardware cvt_pk (T12 recipe)
            float ps = 0.f;
            union { unsigned u[4]; bf16x8 v; } P0, P1;
#pragma unroll
            for (int c = 0; c < 2; c++)
#pragma unroll
                for (int rp = 0; rp < 2; rp++) {
                    float e0 = exp2f(sv[c][2 * rp]         - m_run);
                    float e1 = exp2f(sv[c][2 * rp + 1]     - m_run);
                    float e2 = exp2f(sv[c + 2][2 * rp]     - m_run);
                    float e3 = exp2f(sv[c + 2][2 * rp + 1] - m_run);
                    ps += (e0 + e1) + (e2 + e3);
                    P0.u[c * 2 + rp] = cvtpk(e0, e1);
                    P1.u[c * 2 + rp] = cvtpk(e2, e3);
                }
            l_run += ps;

            // O^T += V~ P~ with matching slot->key map on both operands
            __builtin_amdgcn_s_setprio(1);
#pragma unroll
            for (int cd = 0; cd < 4; cd++) {
                bf16x8 vf0 = *(const bf16x8*)(&Vs[bufi][cd * 16 + l15][((2 * lg)     ^ swq) * 8]);
                bf16x8 vf1 = *(const bf16x8*)(&Vs[bufi][cd * 16 + l15][((2 * lg + 1) ^ swq) * 8]);
                o[cd] = __builtin_amdgcn_mfma_f32_16x16x32_bf16(vf0, P0.v, o[cd], 0, 0, 0);
                o[cd] = __builtin_amdgcn_mfma_f32_16x16x32_bf16(vf1, P1.v, o[cd], 0, 0, 0);
            }
            __builtin_amdgcn_s_setprio(0);
        }
    }

    // epilogue: cross-lane l reduce, normalize, store packed
    float ls = l_run;
    ls += __shfl_xor(ls, 16);
    ls += __shfl_xor(ls, 32);
    float inv = 1.0f / ls;
    const size_t rowbase = ((size_t)(b * T_ + qrow)) * C_ + h * 64;
#pragma unroll
    for (int cd = 0; cd < 4; cd++) {
        unsigned ok2[2];
        ok2[0] = cvtpk(o[cd][0] * inv, o[cd][1] * inv);
        ok2[1] = cvtpk(o[cd][2] * inv, o[cd][3] * inv);
        *(unsigned long long*)(&att[rowbase + cd * 16 + lg * 4]) =
            *(const unsigned long long*)ok2;
    }
}

extern "C" void kernel_launch(void* const* d_in, const int* in_sizes, int n_in,
                              void* d_out, int out_size, void* d_ws, size_t ws_size,
                              hipStream_t stream)
{
    const float* x      = (const float*)d_in[0];
    const float* W_qkv  = (const float*)d_in[1];
    const float* b_qkv  = (const float*)d_in[2];
    const float* W_proj = (const float*)d_in[3];
    const float* b_proj = (const float*)d_in[4];
    float* out = (float*)d_out;

    char* p = (char*)d_ws;
    unsigned short* xbf    = (unsigned short*)p; p += (size_t)8192 * 1024 * 2;  // reused as att out
    unsigned short* wqkvT  = (unsigned short*)p; p += (size_t)3072 * 1024 * 2;
    unsigned short* wprojT = (unsigned short*)p; p += (size_t)1024 * 1024 * 2;
    unsigned short* Qb     = (unsigned short*)p; p += (size_t)8192 * 1024 * 2;
    unsigned short* Kb     = (unsigned short*)p; p += (size_t)8192 * 1024 * 2;
    unsigned short* Vt     = (unsigned short*)p; p += (size_t)8192 * 1024 * 2;  // [B*H, 64, T]

    k_conv<<<8192, 256, 0, stream>>>(x, xbf, 8192 * 1024);
    k_transp<<<dim3(96, 32), 256, 0, stream>>>(W_qkv, wqkvT, 1024, 3072);
    k_transp<<<dim3(32, 32), 256, 0, stream>>>(W_proj, wprojT, 1024, 1024);
    k_qkv<<<512, 512, 0, stream>>>(xbf, wqkvT, b_qkv, Qb, Kb, Vt);
    k_attn<<<1024, 512, 0, stream>>>(Qb, Kb, Vt, xbf);
    k_proj<<<dim3(8, 64), 256, 0, stream>>>(xbf, wprojT, b_proj, out, 8192, 1024, 1024);
}

// Round 18
// 182.079 us; speedup vs baseline: 1.0700x; 1.0242x over previous
//
#include <hip/hip_runtime.h>
#include <hip/hip_bf16.h>

// CausalSelfAttention: B=4, T=2048, C=1024, H=16, HD=64
// Pipeline: x->bf16 | W->bf16^T | QKV GEMM (256x192, ring-4, 512 blocks = 2.0 rounds) |
//           flash attn (r16) | proj GEMM (256x128, ring-4, 256 blocks = 1.0 round)

typedef __attribute__((ext_vector_type(8))) short bf16x8;
typedef __attribute__((ext_vector_type(4))) float f32x4;
typedef __attribute__((ext_vector_type(4))) int int4v;

#define B_ 4
#define T_ 2048
#define C_ 1024
#define H_ 16
#define HD_ 64
#define SCALE_LOG2E 0.18033688011112042f   // (1/8) * log2(e), folded into Q at GEMM epilogue

__device__ __forceinline__ unsigned short f2bf(float f) {
    union { __hip_bfloat16 b; unsigned short u; } c;
    c.b = __float2bfloat16(f);
    return c.u;
}

// hardware packed f32x2 -> bf16x2 (RNE), one VALU op
__device__ __forceinline__ unsigned cvtpk(float lo, float hi) {
    unsigned r;
    asm("v_cvt_pk_bf16_f32 %0, %1, %2" : "=v"(r) : "v"(lo), "v"(hi));
    return r;
}

// ---------------- x f32 -> bf16 ----------------
__global__ __launch_bounds__(256) void k_conv(const float* __restrict__ in,
                                              unsigned short* __restrict__ out, int n) {
    int i = (blockIdx.x * 256 + threadIdx.x) * 4;
    if (i >= n) return;
    float4 v = *(const float4*)(in + i);
    unsigned short r[4] = { f2bf(v.x), f2bf(v.y), f2bf(v.z), f2bf(v.w) };
    *(unsigned long long*)(out + i) = *(const unsigned long long*)r;
}

// ---------------- W [R][Cin] f32 -> out [Cin][R] bf16 (transpose+convert) ----------------
__global__ __launch_bounds__(256) void k_transp(const float* __restrict__ in,
                                                unsigned short* __restrict__ out,
                                                int R, int Cin) {
    __shared__ float t[32][33];
    int bx = blockIdx.x, by = blockIdx.y;
    int j = threadIdx.x & 31, i0 = threadIdx.x >> 5;
#pragma unroll
    for (int k = 0; k < 4; k++) {
        int i = i0 + k * 8;
        t[i][j] = in[(size_t)(by * 32 + i) * Cin + bx * 32 + j];
    }
    __syncthreads();
#pragma unroll
    for (int k = 0; k < 4; k++) {
        int c = i0 + k * 8;
        out[(size_t)(bx * 32 + c) * R + by * 32 + j] = f2bf(t[j][c]);
    }
}

// ---------------- QKV GEMM: 256x192 tile, BK=32, ring-4 counted-vmcnt (r17) ----------
#define QK_K 1024
#define QK_NT 32          // K tiles
__global__ __launch_bounds__(512, 2) void k_qkv(
    const unsigned short* __restrict__ A, const unsigned short* __restrict__ BT,
    const float* __restrict__ bias,
    unsigned short* __restrict__ Qb, unsigned short* __restrict__ Kb,
    unsigned short* __restrict__ Vt)
{
    __shared__ unsigned short lds[4][14336];   // ring: A 256x32 (8192) | B 192x32 (6144)

    const int tid = threadIdx.x;
    const int lane = tid & 63;
    const int w = tid >> 6;              // 0..7
    const int wm2 = w >> 2, wn4 = w & 3;
    const int l15 = lane & 15, lg = lane >> 4;

    // XCD-aware bijective swizzle: 512 blocks = 8 * 64
    const int orig = blockIdx.x;
    const int wg = (orig & 7) * 64 + (orig >> 3);
    const int bm = (wg >> 4) * 256, bn = (wg & 15) * 192;

    const int srow = tid >> 2;           // 0..127
    const int scol = (tid & 3) << 3;     // k-offset in shorts

    f32x4 acc[8][3];
#pragma unroll
    for (int mf = 0; mf < 8; mf++)
#pragma unroll
        for (int nf = 0; nf < 3; nf++) acc[mf][nf] = (f32x4){0.f, 0.f, 0.f, 0.f};

    auto stage = [&](int Tt) {
        const int k0 = Tt << 5;
        const int rr = Tt & 3;
#pragma unroll
        for (int j = 0; j < 2; ++j)
            __builtin_amdgcn_global_load_lds(
                (const __attribute__((address_space(1))) void*)
                    (A + (size_t)(bm + srow + j * 128) * QK_K + k0 + scol),
                (__attribute__((address_space(3))) void*)(&lds[rr][w * 512 + j * 4096]),
                16, 0, 0);
        __builtin_amdgcn_global_load_lds(
            (const __attribute__((address_space(1))) void*)
                (BT + (size_t)(bn + srow) * QK_K + k0 + scol),
            (__attribute__((address_space(3))) void*)(&lds[rr][8192 + w * 512]),
            16, 0, 0);
        if (w < 4)
            __builtin_amdgcn_global_load_lds(
                (const __attribute__((address_space(1))) void*)
                    (BT + (size_t)(bn + 128 + srow) * QK_K + k0 + scol),
                (__attribute__((address_space(3))) void*)(&lds[rr][8192 + 4096 + w * 512]),
                16, 0, 0);
    };

    stage(0); stage(1); stage(2);

#pragma unroll 1
    for (int T = 0; T < QK_NT; ++T) {
        if (T <= QK_NT - 3) {
            if (w < 4) { asm volatile("s_waitcnt vmcnt(8)" ::: "memory"); }
            else       { asm volatile("s_waitcnt vmcnt(6)" ::: "memory"); }
        } else if (T == QK_NT - 2) {
            if (w < 4) { asm volatile("s_waitcnt vmcnt(4)" ::: "memory"); }
            else       { asm volatile("s_waitcnt vmcnt(3)" ::: "memory"); }
        } else {
            asm volatile("s_waitcnt vmcnt(0)" ::: "memory");
        }
        __builtin_amdgcn_s_barrier();    // publish tile T
        if (T <= QK_NT - 4) stage(T + 3);

        const int rr = T & 3;
        const unsigned short* Ald = &lds[rr][0];
        const unsigned short* Bld = &lds[rr][8192];
        bf16x8 af[8], bfr[3];
#pragma unroll
        for (int mf = 0; mf < 8; ++mf)
            af[mf] = *(const bf16x8*)(Ald + (wm2 * 128 + mf * 16 + l15) * 32 + lg * 8);
#pragma unroll
        for (int nf = 0; nf < 3; ++nf)
            bfr[nf] = *(const bf16x8*)(Bld + (wn4 * 48 + nf * 16 + l15) * 32 + lg * 8);

        __builtin_amdgcn_s_setprio(1);
#pragma unroll
        for (int mf = 0; mf < 8; ++mf)
#pragma unroll
            for (int nf = 0; nf < 3; ++nf)
                acc[mf][nf] = __builtin_amdgcn_mfma_f32_16x16x32_bf16(af[mf], bfr[nf], acc[mf][nf], 0, 0, 0);
        __builtin_amdgcn_s_setprio(0);
    }

    // epilogue: bias + scatter Q (pre-scaled) / K bf16 [B,H,T,64], V -> Vt [B,H,64,T]
#pragma unroll
    for (int mf = 0; mf < 8; ++mf) {
#pragma unroll
        for (int nf = 0; nf < 3; ++nf) {
            int col = bn + wn4 * 48 + nf * 16 + l15;
            float bval = bias[col];
            int row0 = bm + wm2 * 128 + mf * 16 + lg * 4;
            float vals[4];
#pragma unroll
            for (int r = 0; r < 4; r++) vals[r] = acc[mf][nf][r] + bval;
            int b = row0 >> 11, t0 = row0 & 2047;
            int which = col >> 10;
            int h = (col & 1023) >> 6, d = col & 63;
            if (which == 2) {
                unsigned short pk[4];
#pragma unroll
                for (int r = 0; r < 4; r++) pk[r] = f2bf(vals[r]);
                *(unsigned long long*)(&Vt[((size_t)(b * H_ + h) * HD_ + d) * T_ + t0]) =
                    *(const unsigned long long*)pk;
            } else {
                unsigned short* dst = which ? Kb : Qb;
                float sc_ = which ? 1.0f : SCALE_LOG2E;
#pragma unroll
                for (int r = 0; r < 4; r++)
                    dst[((size_t)(b * H_ + h) * T_ + t0 + r) * HD_ + d] = f2bf(vals[r] * sc_);
            }
        }
    }
}

// ---------------- proj GEMM: 256x128 tile, BK=32, ring-4 counted-vmcnt --------------
// A = att [8192][1024] bf16, BT = wprojT [1024][1024]. 512 threads = 8 waves (4M x 2N),
// per-wave 64x64 output (4x4 frags), 16 MFMA + 8 ds_read_b128 per K-tile.
// Grid 256 = 32 Mtiles x 8 Ntiles = 1.0 EXACT round at 1 block/CU (96KB LDS).
// Staging per thread per tile: A 2x16B + B 1x16B (128 rows x 4 chunks = 512 = 1/thread)
// -> uniform L=3; ledger: steady vmcnt(6), drain (3), then (0). Same validated ring-4
// schedule as k_qkv: stage(T+3) targets buf (T-1)&3 whose reads finished pre-barrier.
__global__ __launch_bounds__(512, 2) void k_proj(
    const unsigned short* __restrict__ A, const unsigned short* __restrict__ BT,
    const float* __restrict__ bias, float* __restrict__ out)
{
    __shared__ unsigned short lds[4][12288];   // ring: A 256x32 (8192) | B 128x32 (4096)

    const int tid = threadIdx.x;
    const int lane = tid & 63;
    const int w = tid >> 6;              // 0..7
    const int wm4 = w >> 1, wn2 = w & 1;
    const int l15 = lane & 15, lg = lane >> 4;

    // XCD-aware bijective swizzle: 256 blocks = 8 * 32
    const int orig = blockIdx.x;
    const int wg = (orig & 7) * 32 + (orig >> 3);
    const int bm = (wg >> 3) * 256, bn = (wg & 7) * 128;

    const int srow = tid >> 2;           // 0..127
    const int scol = (tid & 3) << 3;     // k-offset in shorts

    f32x4 acc[4][4];
#pragma unroll
    for (int mf = 0; mf < 4; mf++)
#pragma unroll
        for (int nf = 0; nf < 4; nf++) acc[mf][nf] = (f32x4){0.f, 0.f, 0.f, 0.f};

    auto stage = [&](int Tt) {
        const int k0 = Tt << 5;
        const int rr = Tt & 3;
#pragma unroll
        for (int j = 0; j < 2; ++j)
            __builtin_amdgcn_global_load_lds(
                (const __attribute__((address_space(1))) void*)
                    (A + (size_t)(bm + srow + j * 128) * 1024 + k0 + scol),
                (__attribute__((address_space(3))) void*)(&lds[rr][w * 512 + j * 4096]),
                16, 0, 0);
        __builtin_amdgcn_global_load_lds(
            (const __attribute__((address_space(1))) void*)
                (BT + (size_t)(bn + srow) * 1024 + k0 + scol),
            (__attribute__((address_space(3))) void*)(&lds[rr][8192 + w * 512]),
            16, 0, 0);
    };

    stage(0); stage(1); stage(2);        // 9 loads in flight

#pragma unroll 1
    for (int T = 0; T < 32; ++T) {
        if (T <= 29)      { asm volatile("s_waitcnt vmcnt(6)" ::: "memory"); }
        else if (T == 30) { asm volatile("s_waitcnt vmcnt(3)" ::: "memory"); }
        else              { asm volatile("s_waitcnt vmcnt(0)" ::: "memory"); }
        __builtin_amdgcn_s_barrier();    // publish tile T
        if (T <= 28) stage(T + 3);

        const int rr = T & 3;
        const unsigned short* Ald = &lds[rr][0];
        const unsigned short* Bld = &lds[rr][8192];
        bf16x8 af[4], bfr[4];
#pragma unroll
        for (int mf = 0; mf < 4; ++mf)
            af[mf] = *(const bf16x8*)(Ald + (wm4 * 64 + mf * 16 + l15) * 32 + lg * 8);
#pragma unroll
        for (int nf = 0; nf < 4; ++nf)
            bfr[nf] = *(const bf16x8*)(Bld + (wn2 * 64 + nf * 16 + l15) * 32 + lg * 8);

        __builtin_amdgcn_s_setprio(1);
#pragma unroll
        for (int mf = 0; mf < 4; ++mf)
#pragma unroll
            for (int nf = 0; nf < 4; ++nf)
                acc[mf][nf] = __builtin_amdgcn_mfma_f32_16x16x32_bf16(af[mf], bfr[nf], acc[mf][nf], 0, 0, 0);
        __builtin_amdgcn_s_setprio(0);
    }

    // epilogue: bias + f32 store
#pragma unroll
    for (int mf = 0; mf < 4; ++mf) {
#pragma unroll
        for (int nf = 0; nf < 4; ++nf) {
            int col = bn + wn2 * 64 + nf * 16 + l15;
            float bval = bias[col];
            int row0 = bm + wm4 * 64 + mf * 16 + lg * 4;
#pragma unroll
            for (int r = 0; r < 4; r++)
                out[(size_t)(row0 + r) * 1024 + col] = acc[mf][nf][r] + bval;
        }
    }
}

// ---------------- Flash attention (causal): r16 (r14 grid + softmax diet) ----------
__global__ __launch_bounds__(512, 4) void k_attn(
    const unsigned short* __restrict__ Qb, const unsigned short* __restrict__ Kb,
    const unsigned short* __restrict__ Vt, unsigned short* __restrict__ att)
{
    __shared__ unsigned short Ks[2][64][64];   // [buf][key][d], chunk16 ^= key&7
    __shared__ unsigned short Vs[2][64][64];   // [buf][d][newcol], chunk16 ^= d&7

    const int tid = threadIdx.x, lane = tid & 63, w = tid >> 6;   // w 0..7
    const int l15 = lane & 15, lg = lane >> 4;
    const int swq = l15 & 7;
    const int j = blockIdx.x;
    const int bh = j & 63;
    const int b = bh >> 4, h = bh & 15;
    const size_t kqbase = (size_t)bh * T_ * HD_;
    const size_t vtbase = (size_t)bh * HD_ * T_;

    const int r0 = tid >> 3;            // 0..63 staging row (one shot, 512 threads)
    const int mm = tid & 7;             // staging col chunk
    const int c8 = mm * 8;
    const int kch = mm;                               // K chunk (pre-swizzle)
    const int vch = 4 * (mm & 1) + (mm >> 2);         // V chunk half0 (pre-swizzle)
    const int voff = ((mm >> 1) & 1) * 4;             // shorts within chunk
    const int swr = r0 & 7;

    const int t = 15 - (j >> 6);            // longest-first 128-row q-tile
    const int qb = t * 128;
    const int qrow = qb + w * 16 + l15;     // this lane's q-row
    const int dtile = 2 * t + (w >> 2);     // wave-uniform diagonal tile
    const int ktlast = 2 * t + 1;           // block stages tiles 0..ktlast

    bf16x8 qf[2];
#pragma unroll
    for (int s = 0; s < 2; s++)
        qf[s] = *(const bf16x8*)(Qb + kqbase + (size_t)qrow * HD_ + s * 32 + lg * 8);

    f32x4 o[4];                   // o[cd][r] = O^T[d=cd*16+lg*4+r][q=l15]
    float m_run = -1e30f, l_run = 0.f;
#pragma unroll
    for (int c = 0; c < 4; c++) o[c] = (f32x4){0.f, 0.f, 0.f, 0.f};

    // prefetch tile 0
    int4v kreg, vreg;
    kreg = *(const int4v*)(Kb + kqbase + (size_t)r0 * HD_ + c8);
    vreg = *(const int4v*)(Vt + vtbase + (size_t)r0 * T_ + c8);

#pragma unroll 1
    for (int kt = 0; kt <= ktlast; ++kt) {
        const int bufi = kt & 1;
        *(int4v*)(&Ks[bufi][r0][(kch ^ swr) * 8]) = kreg;
        {
            unsigned long long vlo = ((const unsigned long long*)&vreg)[0];
            unsigned long long vhi = ((const unsigned long long*)&vreg)[1];
            *(unsigned long long*)(&Vs[bufi][r0][((vch       ^ swr) * 8) + voff]) = vlo;
            *(unsigned long long*)(&Vs[bufi][r0][(((vch + 2) ^ swr) * 8) + voff]) = vhi;
        }
        if (kt < ktlast) {                  // issue next tile's loads early (T14)
            int nk = (kt + 1) * 64;
            kreg = *(const int4v*)(Kb + kqbase + (size_t)(nk + r0) * HD_ + c8);
            vreg = *(const int4v*)(Vt + vtbase + (size_t)r0 * T_ + nk + c8);
        }
        __syncthreads();                    // single barrier per tile

        if (kt <= dtile) {
            // S^T = K Q^T : sv[c][r] = S[key=kt*64+c*16+lg*4+r][q=l15]
            float sv[4][4];
            const bool diag = (kt == dtile);
            __builtin_amdgcn_s_setprio(1);
#pragma unroll
            for (int c = 0; c < 4; c++) {
                bf16x8 kf0 = *(const bf16x8*)(&Ks[bufi][c * 16 + l15][(lg       ^ swq) * 8]);
                bf16x8 kf1 = *(const bf16x8*)(&Ks[bufi][c * 16 + l15][((4 + lg) ^ swq) * 8]);
                f32x4 s4 = (f32x4){0.f, 0.f, 0.f, 0.f};
                s4 = __builtin_amdgcn_mfma_f32_16x16x32_bf16(kf0, qf[0], s4, 0, 0, 0);
                s4 = __builtin_amdgcn_mfma_f32_16x16x32_bf16(kf1, qf[1], s4, 0, 0, 0);
                if (diag) {
                    int key0 = kt * 64 + c * 16 + lg * 4;
#pragma unroll
                    for (int r = 0; r < 4; r++)
                        sv[c][r] = (key0 + r > qrow) ? -1e30f : s4[r];
                } else {
#pragma unroll
                    for (int r = 0; r < 4; r++) sv[c][r] = s4[r];
                }
            }
            __builtin_amdgcn_s_setprio(0);

            // row max: fmaxf-triples so clang fuses v_max3_f32 (T17)
            float a0 = fmaxf(fmaxf(sv[0][0], sv[0][1]), sv[0][2]);
            float a1 = fmaxf(fmaxf(sv[0][3], sv[1][0]), sv[1][1]);
            float a2 = fmaxf(fmaxf(sv[1][2], sv[1][3]), sv[2][0]);
            float a3 = fmaxf(fmaxf(sv[2][1], sv[2][2]), sv[2][3]);
            float a4 = fmaxf(fmaxf(sv[3][0], sv[3][1]), sv[3][2]);
            float tm = fmaxf(fmaxf(fmaxf(a0, a1), a2), fmaxf(fmaxf(a3, a4), sv[3][3]));
            tm = fmaxf(tm, __shfl_xor(tm, 16));
            tm = fmaxf(tm, __shfl_xor(tm, 32));

            // defer-max (T13): rescale only when a row's max grew past THR=8
            if (__any(tm - m_run > 8.f)) {
                float mn = fmaxf(m_run, tm);
                float alpha = exp2f(m_run - mn);
                m_run = mn;
                l_run *= alpha;
#pragma unroll
                for (int cd = 0; cd < 4; cd++)
#pragma unroll
                    for (int r = 0; r < 4; r++) o[cd][r] *= alpha;
            }

            // P in registers (kappa slot order), packed by hardware cvt_pk (T12 recipe)
            float ps = 0.f;
            union { unsigned u[4]; bf16x8 v; } P0, P1;
#pragma unroll
            for (int c = 0; c < 2; c++)
#pragma unroll
                for (int rp = 0; rp < 2; rp++) {
                    float e0 = exp2f(sv[c][2 * rp]         - m_run);
                    float e1 = exp2f(sv[c][2 * rp + 1]     - m_run);
                    float e2 = exp2f(sv[c + 2][2 * rp]     - m_run);
                    float e3 = exp2f(sv[c + 2][2 * rp + 1] - m_run);
                    ps += (e0 + e1) + (e2 + e3);
                    P0.u[c * 2 + rp] = cvtpk(e0, e1);
                    P1.u[c * 2 + rp] = cvtpk(e2, e3);
                }
            l_run += ps;

            // O^T += V~ P~ with matching slot->key map on both operands
            __builtin_amdgcn_s_setprio(1);
#pragma unroll
            for (int cd = 0; cd < 4; cd++) {
                bf16x8 vf0 = *(const bf16x8*)(&Vs[bufi][cd * 16 + l15][((2 * lg)     ^ swq) * 8]);
                bf16x8 vf1 = *(const bf16x8*)(&Vs[bufi][cd * 16 + l15][((2 * lg + 1) ^ swq) * 8]);
                o[cd] = __builtin_amdgcn_mfma_f32_16x16x32_bf16(vf0, P0.v, o[cd], 0, 0, 0);
                o[cd] = __builtin_amdgcn_mfma_f32_16x16x32_bf16(vf1, P1.v, o[cd], 0, 0, 0);
            }
            __builtin_amdgcn_s_setprio(0);
        }
    }

    // epilogue: cross-lane l reduce, normalize, store packed
    float ls = l_run;
    ls += __shfl_xor(ls, 16);
    ls += __shfl_xor(ls, 32);
    float inv = 1.0f / ls;
    const size_t rowbase = ((size_t)(b * T_ + qrow)) * C_ + h * 64;
#pragma unroll
    for (int cd = 0; cd < 4; cd++) {
        unsigned ok2[2];
        ok2[0] = cvtpk(o[cd][0] * inv, o[cd][1] * inv);
        ok2[1] = cvtpk(o[cd][2] * inv, o[cd][3] * inv);
        *(unsigned long long*)(&att[rowbase + cd * 16 + lg * 4]) =
            *(const unsigned long long*)ok2;
    }
}

extern "C" void kernel_launch(void* const* d_in, const int* in_sizes, int n_in,
                              void* d_out, int out_size, void* d_ws, size_t ws_size,
                              hipStream_t stream)
{
    const float* x      = (const float*)d_in[0];
    const float* W_qkv  = (const float*)d_in[1];
    const float* b_qkv  = (const float*)d_in[2];
    const float* W_proj = (const float*)d_in[3];
    const float* b_proj = (const float*)d_in[4];
    float* out = (float*)d_out;

    char* p = (char*)d_ws;
    unsigned short* xbf    = (unsigned short*)p; p += (size_t)8192 * 1024 * 2;  // reused as att out
    unsigned short* wqkvT  = (unsigned short*)p; p += (size_t)3072 * 1024 * 2;
    unsigned short* wprojT = (unsigned short*)p; p += (size_t)1024 * 1024 * 2;
    unsigned short* Qb     = (unsigned short*)p; p += (size_t)8192 * 1024 * 2;
    unsigned short* Kb     = (unsigned short*)p; p += (size_t)8192 * 1024 * 2;
    unsigned short* Vt     = (unsigned short*)p; p += (size_t)8192 * 1024 * 2;  // [B*H, 64, T]

    k_conv<<<8192, 256, 0, stream>>>(x, xbf, 8192 * 1024);
    k_transp<<<dim3(96, 32), 256, 0, stream>>>(W_qkv, wqkvT, 1024, 3072);
    k_transp<<<dim3(32, 32), 256, 0, stream>>>(W_proj, wprojT, 1024, 1024);
    k_qkv<<<512, 512, 0, stream>>>(xbf, wqkvT, b_qkv, Qb, Kb, Vt);
    k_attn<<<1024, 512, 0, stream>>>(Qb, Kb, Vt, xbf);
    k_proj<<<256, 512, 0, stream>>>(xbf, wprojT, b_proj, out);
}